// Round 1
// baseline (1002.061 us; speedup 1.0000x reference)
//
#include <hip/hip_runtime.h>

// TreeTransformer on MI355X: bf16 MFMA pipeline.
// B=32,A=64 -> S=2048 sequences, N=121 tokens, H=128, heads=4(hd=32), NL=2, OUT=256.
// Layout rule for all LDS fragment tiles: row stride 136 ushorts (272B=17*16B):
// 16B-aligned for ds_read_b128 and bank-balanced for the A/B fragment pattern.

typedef unsigned short u16;
typedef __attribute__((ext_vector_type(8))) short bf16x8;  // 8 bf16 (4 VGPRs)
typedef __attribute__((ext_vector_type(4))) float f32x4;

#define NTOK 121
#define HD 128
#define S_TOT 2048
#define EPSF 1e-5f

__device__ inline u16 f2bf(float f) {  // round-to-nearest-even fp32->bf16
  unsigned u = __float_as_uint(f);
  return (u16)((u + 0x7FFFu + ((u >> 16) & 1u)) >> 16);
}
__device__ inline float bf2f(u16 h) { return __uint_as_float(((unsigned)h) << 16); }

__device__ inline f32x4 mfma16(bf16x8 a, bf16x8 b, f32x4 c) {
  return __builtin_amdgcn_mfma_f32_16x16x32_bf16(a, b, c, 0, 0, 0);
}

// ---------------- weight fp32 -> bf16 conversion -------------------------
// concatenated: qkv(98304) | proj(32768) | ff1(32768) | ff2(32768) | wout(3964928)
__global__ __launch_bounds__(256) void convw_kernel(
    const float* __restrict__ qkvw, const float* __restrict__ projw,
    const float* __restrict__ ff1w, const float* __restrict__ ff2w,
    const float* __restrict__ wout, u16* __restrict__ dst) {
  int i = blockIdx.x * 256 + threadIdx.x;  // grid sized exactly 4161536/256
  float v;
  if (i < 98304) v = qkvw[i];
  else if (i < 131072) v = projw[i - 98304];
  else if (i < 163840) v = ff1w[i - 131072];
  else if (i < 196608) v = ff2w[i - 163840];
  else v = wout[i - 196608];
  dst[i] = f2bf(v);
}

// ---------------- input projection + tree PE + permutation ---------------
__global__ __launch_bounds__(256) void inproj_kernel(
    const float* __restrict__ forest, const int* __restrict__ adj,
    const int* __restrict__ perm, const float* __restrict__ WIN,
    const float* __restrict__ BIN, u16* __restrict__ X) {
  __shared__ float wf[128 * 12];
  __shared__ float fr[121 * 12];
  __shared__ float pe[121 * 12];
  __shared__ int pm[121];
  int s = blockIdx.x, tid = threadIdx.x;
  const float* fg = forest + (size_t)s * (NTOK * 12);
  const int* ag = adj + (size_t)s * (120 * 3);
  for (int i = tid; i < 128 * 12; i += 256) wf[i] = WIN[i];
  for (int i = tid; i < 121 * 12; i += 256) { fr[i] = fg[i]; pe[i] = 0.f; }
  if (tid < 121) pm[tid] = perm[tid];
  __syncthreads();
  if (tid > 0 && tid < 121) {
    int n = tid;
    int l = (n <= 3) ? 1 : (n <= 12) ? 2 : (n <= 39) ? 3 : 4;  // level by index range
    int cur = n;
    while (cur > 0) {  // walk to root, set bit (level-1)*3 + branch at each hop
      int par = ag[(cur - 1) * 3];
      int br = ag[(cur - 1) * 3 + 2];
      pe[n * 12 + (l - 1) * 3 + br] = 1.f;
      cur = par; l--;
    }
  }
  __syncthreads();
  int h = tid & 127;
  for (int base = 0; base < 121; base += 2) {
    int i = base + (tid >> 7);
    if (i < 121) {
      int node = pm[i];  // x_perm[:, i] = x[:, perm[i]]
      float v = BIN[h];
#pragma unroll
      for (int k = 0; k < 12; ++k) v += fr[node * 12 + k] * wf[h * 12 + k];
      if (h < 12) v += pe[node * 12 + h];  // PE only touches channels 0..11
      X[(size_t)s * (NTOK * HD) + i * HD + h] = f2bf(v);
    }
  }
}

// ---------------- fused per-sequence attention ---------------------------
// One WG (256 thr / 4 waves) per sequence. Per head: QKV GEMM (x in LDS,
// weights streamed from L2) -> logits -> fp32 softmax -> P@V. LDS = 64000B.
__global__ __launch_bounds__(256, 2) void attn_kernel(
    const u16* __restrict__ X, u16* __restrict__ O,
    const u16* __restrict__ WQKV, const float* __restrict__ QKVB, int layer) {
  __shared__ u16 xs[128 * 136];   // x, rows 121..127 zero-padded
  __shared__ u16 qk[10240];       // qs[128*40] | ks[128*40]; later overlaid by P tiles
  __shared__ u16 vsT[32 * 136];   // V transposed: [dim][token]
  int s = blockIdx.x, tid = threadIdx.x;
  int wave = tid >> 6, lane = tid & 63, l16 = lane & 15, quad = lane >> 4;
  const u16* xg = X + (size_t)s * (NTOK * HD);
  for (int c = tid; c < 128 * 16; c += 256) {
    int row = c >> 4, g = c & 15;
    uint4 v;
    if (row < NTOK) v = *(const uint4*)(xg + row * HD + g * 8);
    else v = make_uint4(0, 0, 0, 0);
    *(uint4*)(xs + row * 136 + g * 8) = v;
  }
  __syncthreads();
  u16* qs = qk;
  u16* ks = qk + 128 * 40;
  const f32x4 fz = {0.f, 0.f, 0.f, 0.f};
  for (int hh = 0; hh < 4; ++hh) {
    // --- QKV for this head: 48 tiles (q,k,v x 8Mt x 2Nt), 12 per wave ---
    for (int tt = wave; tt < 48; tt += 4) {
      int mat = tt >> 4, rem = tt & 15, mt = rem >> 1, nt = rem & 1;
      f32x4 acc = fz;
      const u16* wb = WQKV +
          ((size_t)(layer * 384 + mat * 128 + hh * 32 + nt * 16 + l16)) * HD + quad * 8;
      const u16* ab = xs + (mt * 16 + l16) * 136 + quad * 8;
#pragma unroll
      for (int k = 0; k < 4; ++k)
        acc = mfma16(*(const bf16x8*)(ab + k * 32), *(const bf16x8*)(wb + k * 32), acc);
      float bias = QKVB[layer * 384 + mat * 128 + hh * 32 + nt * 16 + l16];
      int col = nt * 16 + l16;
#pragma unroll
      for (int r = 0; r < 4; ++r) {
        int row = mt * 16 + quad * 4 + r;
        float v = acc[r] + bias;
        if (mat == 0)      qs[row * 40 + col] = f2bf(v * 0.17677669529663687f);  // 1/sqrt(32)
        else if (mat == 1) ks[row * 40 + col] = f2bf(v);
        else               vsT[col * 136 + row] = f2bf(v);
      }
    }
    __syncthreads();
    // --- logits: wave owns M-tiles 2w, 2w+1 (rows 32w..32w+31) ---
    f32x4 lacc[2][8];
    for (int mi = 0; mi < 2; ++mi) {
      int mt = wave * 2 + mi;
      bf16x8 af = *(const bf16x8*)(qs + (mt * 16 + l16) * 40 + quad * 8);
#pragma unroll
      for (int nt = 0; nt < 8; ++nt)
        lacc[mi][nt] = mfma16(af, *(const bf16x8*)(ks + (nt * 16 + l16) * 40 + quad * 8), fz);
    }
    __syncthreads();  // everyone done reading qs/ks -> safe to overlay P tiles
    u16* ps = qk + wave * 2176;  // per-wave private 16x136 P tile (in qk region)
    for (int mi = 0; mi < 2; ++mi) {
      int mt = wave * 2 + mi;
      // fp32 softmax per row (4 rows/lane), reduce over 16 lanes of the quad
#pragma unroll
      for (int r = 0; r < 4; ++r) {
        float mx = -1e30f;
#pragma unroll
        for (int nt = 0; nt < 8; ++nt) {
          int col = nt * 16 + l16;
          if (col < NTOK) mx = fmaxf(mx, lacc[mi][nt][r]);
        }
        for (int m = 1; m <= 8; m <<= 1) mx = fmaxf(mx, __shfl_xor(mx, m, 64));
        float pv[8]; float sum = 0.f;
#pragma unroll
        for (int nt = 0; nt < 8; ++nt) {
          int col = nt * 16 + l16;
          float p = (col < NTOK) ? __expf(lacc[mi][nt][r] - mx) : 0.f;
          pv[nt] = p; sum += p;
        }
        for (int m = 1; m <= 8; m <<= 1) sum += __shfl_xor(sum, m, 64);
        float rinv = 1.f / sum;
        int lr = quad * 4 + r;
#pragma unroll
        for (int nt = 0; nt < 8; ++nt)
          ps[lr * 136 + nt * 16 + l16] = f2bf(pv[nt] * rinv);
      }
      // --- P @ V for this M-tile (wave-private LDS, in-order per wave) ---
#pragma unroll
      for (int nt = 0; nt < 2; ++nt) {
        f32x4 acc = fz;
#pragma unroll
        for (int k = 0; k < 4; ++k) {
          bf16x8 af = *(const bf16x8*)(ps + l16 * 136 + k * 32 + quad * 8);
          bf16x8 bf = *(const bf16x8*)(vsT + (nt * 16 + l16) * 136 + k * 32 + quad * 8);
          acc = mfma16(af, bf, acc);
        }
#pragma unroll
        for (int r = 0; r < 4; ++r) {
          int row = mt * 16 + quad * 4 + r;
          if (row < NTOK)
            O[(size_t)s * (NTOK * HD) + row * HD + hh * 32 + nt * 16 + l16] = f2bf(acc[r]);
        }
      }
    }
    __syncthreads();  // before next head rewrites qk/vsT
  }
}

// ---------------- proj GEMM + residual + LN1 (in-place on X) -------------
__global__ __launch_bounds__(256) void projln_kernel(
    u16* __restrict__ X, const u16* __restrict__ O,
    const u16* __restrict__ WP, const float* __restrict__ PB,
    const float* __restrict__ G, const float* __restrict__ Bt, int layer) {
  __shared__ u16 as_[32 * 136];
  __shared__ float ct[32 * 132];
  int r0 = blockIdx.x * 32, tid = threadIdx.x;
  int wave = tid >> 6, lane = tid & 63, l16 = lane & 15, quad = lane >> 4;
  const f32x4 fz = {0.f, 0.f, 0.f, 0.f};
  for (int c = tid; c < 32 * 16; c += 256) {
    int row = c >> 4, g = c & 15;
    *(uint4*)(as_ + row * 136 + g * 8) = *(const uint4*)(O + (size_t)(r0 + row) * HD + g * 8);
  }
  __syncthreads();
  f32x4 acc[2][2] = {{fz, fz}, {fz, fz}};
#pragma unroll
  for (int k = 0; k < 4; ++k) {
    bf16x8 a0 = *(const bf16x8*)(as_ + l16 * 136 + k * 32 + quad * 8);
    bf16x8 a1 = *(const bf16x8*)(as_ + (16 + l16) * 136 + k * 32 + quad * 8);
#pragma unroll
    for (int n = 0; n < 2; ++n) {
      int nt = wave * 2 + n;
      bf16x8 bf = *(const bf16x8*)(WP + ((size_t)(layer * 128 + nt * 16 + l16)) * HD + k * 32 + quad * 8);
      acc[0][n] = mfma16(a0, bf, acc[0][n]);
      acc[1][n] = mfma16(a1, bf, acc[1][n]);
    }
  }
  for (int mt = 0; mt < 2; ++mt)
    for (int n = 0; n < 2; ++n) {
      int nt = wave * 2 + n;
#pragma unroll
      for (int r = 0; r < 4; ++r)
        ct[(mt * 16 + quad * 4 + r) * 132 + nt * 16 + l16] = acc[mt][n][r];
    }
  __syncthreads();
  int row = tid >> 3, l8 = tid & 7;
  size_t R = (size_t)(r0 + row);
  float v[16], sum = 0.f, ssq = 0.f;
#pragma unroll
  for (int i = 0; i < 16; ++i) {
    int c = l8 * 16 + i;
    float t = ct[row * 132 + c] + PB[layer * 128 + c] + bf2f(X[R * HD + c]);
    v[i] = t; sum += t; ssq += t * t;
  }
  for (int m = 1; m <= 4; m <<= 1) { sum += __shfl_xor(sum, m, 64); ssq += __shfl_xor(ssq, m, 64); }
  float mean = sum * (1.f / 128.f);
  float var = ssq * (1.f / 128.f) - mean * mean;
  float rstd = rsqrtf(var + EPSF);
#pragma unroll
  for (int i = 0; i < 16; ++i) {
    int c = l8 * 16 + i;
    X[R * HD + c] = f2bf((v[i] - mean) * rstd * G[layer * 128 + c] + Bt[layer * 128 + c]);
  }
}

// ---------------- ff1+relu+ff2 + residual + LN2 (in-place on X) ----------
__global__ __launch_bounds__(256) void ffn_kernel(
    u16* __restrict__ X,
    const u16* __restrict__ W1, const float* __restrict__ B1,
    const u16* __restrict__ W2, const float* __restrict__ B2,
    const float* __restrict__ G, const float* __restrict__ Bt, int layer) {
  __shared__ u16 as_[32 * 136];
  __shared__ u16 hs[32 * 136];
  __shared__ float ct[32 * 132];
  int r0 = blockIdx.x * 32, tid = threadIdx.x;
  int wave = tid >> 6, lane = tid & 63, l16 = lane & 15, quad = lane >> 4;
  const f32x4 fz = {0.f, 0.f, 0.f, 0.f};
  for (int c = tid; c < 32 * 16; c += 256) {
    int row = c >> 4, g = c & 15;
    *(uint4*)(as_ + row * 136 + g * 8) = *(const uint4*)(X + (size_t)(r0 + row) * HD + g * 8);
  }
  __syncthreads();
  f32x4 acc[2][2] = {{fz, fz}, {fz, fz}};
#pragma unroll
  for (int k = 0; k < 4; ++k) {
    bf16x8 a0 = *(const bf16x8*)(as_ + l16 * 136 + k * 32 + quad * 8);
    bf16x8 a1 = *(const bf16x8*)(as_ + (16 + l16) * 136 + k * 32 + quad * 8);
#pragma unroll
    for (int n = 0; n < 2; ++n) {
      int nt = wave * 2 + n;
      bf16x8 bf = *(const bf16x8*)(W1 + ((size_t)(layer * 128 + nt * 16 + l16)) * HD + k * 32 + quad * 8);
      acc[0][n] = mfma16(a0, bf, acc[0][n]);
      acc[1][n] = mfma16(a1, bf, acc[1][n]);
    }
  }
  for (int mt = 0; mt < 2; ++mt)
    for (int n = 0; n < 2; ++n) {
      int nt = wave * 2 + n;
      int col = nt * 16 + l16;
      float b1 = B1[layer * 128 + col];
#pragma unroll
      for (int r = 0; r < 4; ++r)
        hs[(mt * 16 + quad * 4 + r) * 136 + col] = f2bf(fmaxf(acc[mt][n][r] + b1, 0.f));
    }
  __syncthreads();
  f32x4 acc2[2][2] = {{fz, fz}, {fz, fz}};
#pragma unroll
  for (int k = 0; k < 4; ++k) {
    bf16x8 a0 = *(const bf16x8*)(hs + l16 * 136 + k * 32 + quad * 8);
    bf16x8 a1 = *(const bf16x8*)(hs + (16 + l16) * 136 + k * 32 + quad * 8);
#pragma unroll
    for (int n = 0; n < 2; ++n) {
      int nt = wave * 2 + n;
      bf16x8 bf = *(const bf16x8*)(W2 + ((size_t)(layer * 128 + nt * 16 + l16)) * HD + k * 32 + quad * 8);
      acc2[0][n] = mfma16(a0, bf, acc2[0][n]);
      acc2[1][n] = mfma16(a1, bf, acc2[1][n]);
    }
  }
  for (int mt = 0; mt < 2; ++mt)
    for (int n = 0; n < 2; ++n) {
      int nt = wave * 2 + n;
#pragma unroll
      for (int r = 0; r < 4; ++r)
        ct[(mt * 16 + quad * 4 + r) * 132 + nt * 16 + l16] = acc2[mt][n][r];
    }
  __syncthreads();
  int row = tid >> 3, l8 = tid & 7;
  size_t R = (size_t)(r0 + row);
  float v[16], sum = 0.f, ssq = 0.f;
#pragma unroll
  for (int i = 0; i < 16; ++i) {
    int c = l8 * 16 + i;
    float t = ct[row * 132 + c] + B2[layer * 128 + c] + bf2f(as_[row * 136 + c]);
    v[i] = t; sum += t; ssq += t * t;
  }
  for (int m = 1; m <= 4; m <<= 1) { sum += __shfl_xor(sum, m, 64); ssq += __shfl_xor(ssq, m, 64); }
  float mean = sum * (1.f / 128.f);
  float var = ssq * (1.f / 128.f) - mean * mean;
  float rstd = rsqrtf(var + EPSF);
#pragma unroll
  for (int i = 0; i < 16; ++i) {
    int c = l8 * 16 + i;
    X[R * HD + c] = f2bf((v[i] - mean) * rstd * G[layer * 128 + c] + Bt[layer * 128 + c]);
  }
}

// ---------------- final GEMM (M=2048,K=15488,N=256), split-K=16 ----------
__global__ __launch_bounds__(256, 2) void outgemm_kernel(
    const u16* __restrict__ X, const u16* __restrict__ WO, float* __restrict__ PART) {
  __shared__ u16 as_[64 * 136];
  int mtile = blockIdx.x, j = blockIdx.y;
  int tid = threadIdx.x, wave = tid >> 6, lane = tid & 63, l16 = lane & 15, quad = lane >> 4;
  int s0 = mtile * 64;
  int k0 = (j * 484) / 16, k1 = ((j + 1) * 484) / 16;  // k-steps of 32 over K=15488
  const f32x4 fz = {0.f, 0.f, 0.f, 0.f};
  f32x4 acc[4][4];
  for (int a = 0; a < 4; ++a) for (int b = 0; b < 4; ++b) acc[a][b] = fz;
  for (int kb = k0; kb < k1; kb += 4) {
    int nst = (k1 - kb < 4) ? (k1 - kb) : 4;
    __syncthreads();
    int chunks = 64 * 4 * nst;
    for (int c = tid; c < chunks; c += 256) {
      int row = c / (4 * nst), g = c % (4 * nst);
      *(uint4*)(as_ + row * 136 + g * 8) =
          *(const uint4*)(X + (size_t)(s0 + row) * 15488 + kb * 32 + g * 8);
    }
    __syncthreads();
    for (int kk = 0; kk < nst; ++kk) {
      bf16x8 af[4];
#pragma unroll
      for (int mt = 0; mt < 4; ++mt)
        af[mt] = *(const bf16x8*)(as_ + (mt * 16 + l16) * 136 + kk * 32 + quad * 8);
#pragma unroll
      for (int n = 0; n < 4; ++n) {
        int nt = wave * 4 + n;
        bf16x8 bf = *(const bf16x8*)(WO + (size_t)(nt * 16 + l16) * 15488 +
                                     (size_t)(kb + kk) * 32 + quad * 8);
#pragma unroll
        for (int mt = 0; mt < 4; ++mt) acc[mt][n] = mfma16(af[mt], bf, acc[mt][n]);
      }
    }
  }
  for (int mt = 0; mt < 4; ++mt)
    for (int n = 0; n < 4; ++n) {
      int nt = wave * 4 + n;
#pragma unroll
      for (int r = 0; r < 4; ++r) {
        int row = s0 + mt * 16 + quad * 4 + r;
        PART[((size_t)j * 2048 + row) * 256 + nt * 16 + l16] = acc[mt][n][r];
      }
    }
}

// ---------------- reduce split-K partials + bias + final LN --------------
__global__ __launch_bounds__(256) void lnf_kernel(
    const float* __restrict__ PART, const float* __restrict__ BO,
    const float* __restrict__ G, const float* __restrict__ Bt, float* __restrict__ OUT) {
  int s = blockIdx.x * 4 + (threadIdx.x >> 6);  // one wave per sequence
  int lane = threadIdx.x & 63;
  float v[4], sum = 0.f, ssq = 0.f;
#pragma unroll
  for (int i = 0; i < 4; ++i) {
    int c = lane + i * 64;
    float t = BO[c];
    for (int jj = 0; jj < 16; ++jj) t += PART[((size_t)jj * 2048 + s) * 256 + c];
    v[i] = t; sum += t; ssq += t * t;
  }
  for (int m = 1; m <= 32; m <<= 1) { sum += __shfl_xor(sum, m, 64); ssq += __shfl_xor(ssq, m, 64); }
  float mean = sum * (1.f / 256.f);
  float var = ssq * (1.f / 256.f) - mean * mean;
  float rstd = rsqrtf(var + EPSF);
#pragma unroll
  for (int i = 0; i < 4; ++i) {
    int c = lane + i * 64;
    OUT[(size_t)s * 256 + c] = (v[i] - mean) * rstd * G[c] + Bt[c];
  }
}

extern "C" void kernel_launch(void* const* d_in, const int* in_sizes, int n_in,
                              void* d_out, int out_size, void* d_ws, size_t ws_size,
                              hipStream_t stream) {
  const float* forest = (const float*)d_in[0];
  const int* adj      = (const int*)d_in[1];
  const int* perm     = (const int*)d_in[2];
  const float* w_in   = (const float*)d_in[3];
  const float* b_in   = (const float*)d_in[4];
  const float* qkv_w  = (const float*)d_in[5];
  const float* qkv_b  = (const float*)d_in[6];
  const float* proj_w = (const float*)d_in[7];
  const float* proj_b = (const float*)d_in[8];
  const float* ff1_w  = (const float*)d_in[9];
  const float* ff1_b  = (const float*)d_in[10];
  const float* ff2_w  = (const float*)d_in[11];
  const float* ff2_b  = (const float*)d_in[12];
  const float* ln1_g  = (const float*)d_in[13];
  const float* ln1_b  = (const float*)d_in[14];
  const float* ln2_g  = (const float*)d_in[15];
  const float* ln2_b  = (const float*)d_in[16];
  const float* w_out  = (const float*)d_in[17];
  const float* b_out  = (const float*)d_in[18];
  const float* lnf_g  = (const float*)d_in[19];
  const float* lnf_b  = (const float*)d_in[20];

  // workspace map (bytes): bf16 weights 8,323,072 | X 63,438,848 | O 63,438,848 | PART 33,554,432
  char* ws = (char*)d_ws;
  u16* WB = (u16*)ws;
  u16* X  = (u16*)(ws + 8323072);
  u16* O  = (u16*)(ws + 8323072 + 63438848);
  float* PART = (float*)(ws + 8323072 + 2 * (size_t)63438848);

  u16* WQKV  = WB;
  u16* WPROJ = WB + 98304;
  u16* WFF1  = WB + 131072;
  u16* WFF2  = WB + 163840;
  u16* WOUT  = WB + 196608;

  convw_kernel<<<16256, 256, 0, stream>>>(qkv_w, proj_w, ff1_w, ff2_w, w_out, WB);
  inproj_kernel<<<2048, 256, 0, stream>>>(forest, adj, perm, w_in, b_in, X);
  for (int layer = 0; layer < 2; ++layer) {
    attn_kernel<<<2048, 256, 0, stream>>>(X, O, WQKV, qkv_b, layer);
    projln_kernel<<<7744, 256, 0, stream>>>(X, O, WPROJ, proj_b, ln1_g, ln1_b, layer);
    ffn_kernel<<<7744, 256, 0, stream>>>(X, WFF1, ff1_b, WFF2, ff2_b, ln2_g, ln2_b, layer);
  }
  outgemm_kernel<<<dim3(32, 16), 256, 0, stream>>>(X, WOUT, PART);
  lnf_kernel<<<512, 256, 0, stream>>>(PART, b_out, lnf_g, lnf_b, (float*)d_out);
}

// Round 2
// 892.654 us; speedup vs baseline: 1.1226x; 1.1226x over previous
//
#include <hip/hip_runtime.h>

// TreeTransformer on MI355X: bf16 MFMA pipeline.
// B=32,A=64 -> S=2048 sequences, N=121 tokens, H=128, heads=4(hd=32), NL=2, OUT=256.
// r1: barrier-free attention. One wave owns (head, token-half); K/V/P live in
// XOR-swizzled compact LDS (48KB/WG -> 3 WG/CU); a single __syncthreads per WG.

typedef unsigned short u16;
typedef __attribute__((ext_vector_type(8))) short bf16x8;  // 8 bf16 (4 VGPRs)
typedef __attribute__((ext_vector_type(4))) float f32x4;

#define NTOK 121
#define HD 128
#define S_TOT 2048
#define EPSF 1e-5f

__device__ inline u16 f2bf(float f) {  // round-to-nearest-even fp32->bf16
  unsigned u = __float_as_uint(f);
  return (u16)((u + 0x7FFFu + ((u >> 16) & 1u)) >> 16);
}
__device__ inline float bf2f(u16 h) { return __uint_as_float(((unsigned)h) << 16); }

__device__ inline f32x4 mfma16(bf16x8 a, bf16x8 b, f32x4 c) {
  return __builtin_amdgcn_mfma_f32_16x16x32_bf16(a, b, c, 0, 0, 0);
}

// ---------------- weight fp32 -> bf16 conversion -------------------------
// concatenated: qkv(98304) | proj(32768) | ff1(32768) | ff2(32768) | wout(3964928)
__global__ __launch_bounds__(256) void convw_kernel(
    const float* __restrict__ qkvw, const float* __restrict__ projw,
    const float* __restrict__ ff1w, const float* __restrict__ ff2w,
    const float* __restrict__ wout, u16* __restrict__ dst) {
  int i = blockIdx.x * 256 + threadIdx.x;  // grid sized exactly 4161536/256
  float v;
  if (i < 98304) v = qkvw[i];
  else if (i < 131072) v = projw[i - 98304];
  else if (i < 163840) v = ff1w[i - 131072];
  else if (i < 196608) v = ff2w[i - 163840];
  else v = wout[i - 196608];
  dst[i] = f2bf(v);
}

// ---------------- input projection + tree PE + permutation ---------------
__global__ __launch_bounds__(256) void inproj_kernel(
    const float* __restrict__ forest, const int* __restrict__ adj,
    const int* __restrict__ perm, const float* __restrict__ WIN,
    const float* __restrict__ BIN, u16* __restrict__ X) {
  __shared__ float wf[128 * 12];
  __shared__ float fr[121 * 12];
  __shared__ float pe[121 * 12];
  __shared__ int pm[121];
  int s = blockIdx.x, tid = threadIdx.x;
  const float* fg = forest + (size_t)s * (NTOK * 12);
  const int* ag = adj + (size_t)s * (120 * 3);
  for (int i = tid; i < 128 * 12; i += 256) wf[i] = WIN[i];
  for (int i = tid; i < 121 * 12; i += 256) { fr[i] = fg[i]; pe[i] = 0.f; }
  if (tid < 121) pm[tid] = perm[tid];
  __syncthreads();
  if (tid > 0 && tid < 121) {
    int n = tid;
    int l = (n <= 3) ? 1 : (n <= 12) ? 2 : (n <= 39) ? 3 : 4;  // level by index range
    int cur = n;
    while (cur > 0) {  // walk to root, set bit (level-1)*3 + branch at each hop
      int par = ag[(cur - 1) * 3];
      int br = ag[(cur - 1) * 3 + 2];
      pe[n * 12 + (l - 1) * 3 + br] = 1.f;
      cur = par; l--;
    }
  }
  __syncthreads();
  int h = tid & 127;
  for (int base = 0; base < 121; base += 2) {
    int i = base + (tid >> 7);
    if (i < 121) {
      int node = pm[i];  // x_perm[:, i] = x[:, perm[i]]
      float v = BIN[h];
#pragma unroll
      for (int k = 0; k < 12; ++k) v += fr[node * 12 + k] * wf[h * 12 + k];
      if (h < 12) v += pe[node * 12 + h];  // PE only touches channels 0..11
      X[(size_t)s * (NTOK * HD) + i * HD + h] = f2bf(v);
    }
  }
}

// ---------------- barrier-free fused attention ---------------------------
// Grid 4096: WG = (seq, head-pair). 4 waves; wave = (head slot hs = wave>>1,
// half = wave&1). Each wave builds K,V for its 64 tokens of its head (A-frags
// straight from global X, W from L2), ONE barrier, then processes its 4 query
// M-tiles: Q -> logits -> softmax(fp32, exp2-domain) -> P@V -> O.
// LDS 49152B: per head-slot K[128x32] 8KB + Vt[32x128] 8KB (XOR-swizzled
// compact), per wave P/q 4KB. 3 WG/CU.
__global__ __launch_bounds__(256, 3) void attn_kernel(
    const u16* __restrict__ X, u16* __restrict__ O,
    const u16* __restrict__ WQKV, const float* __restrict__ QKVB, int layer) {
  __shared__ u16 lds[24576];
  int tid = threadIdx.x;
  int wave = tid >> 6, lane = tid & 63, l16 = lane & 15, quad = lane >> 4;
  int seq = blockIdx.x >> 1;
  int head = ((blockIdx.x & 1) << 1) | (wave >> 1);
  int half = wave & 1;
  int hs = wave >> 1;
  u16* Kh = lds + hs * 4096;          // K[t][d]: t*32 + ((d>>3 ^ t&3)<<3) + (d&7)
  u16* Vh = lds + 8192 + hs * 4096;   // Vt[d][t]: d*128 + ((t>>3 ^ d&15)<<3) + (t&7)
  u16* Pw = lds + 16384 + wave * 2048;  // P[q][t] (q-tile overlaid at base)
  const u16* Xs = X + (size_t)seq * (NTOK * HD);
  const f32x4 fz = {0.f, 0.f, 0.f, 0.f};
  const int wbase = layer * 384 + head * 32;
  const u16* WQ = WQKV + (size_t)wbase * HD;
  const u16* WK = WQKV + (size_t)(wbase + 128) * HD;
  const u16* WV = WQKV + (size_t)(wbase + 256) * HD;

  // ---- phase 1: K, V^T for tokens [half*64, half*64+64) of this head ----
  for (int mt = 0; mt < 4; ++mt) {
    int tb = half * 64 + mt * 16;
    int arow = tb + l16; if (arow > 120) arow = 120;  // pad rows: any valid data
    bf16x8 a[4];
#pragma unroll
    for (int k = 0; k < 4; ++k)
      a[k] = *(const bf16x8*)(Xs + (size_t)arow * HD + k * 32 + quad * 8);
#pragma unroll
    for (int nt = 0; nt < 2; ++nt) {
      f32x4 kacc = fz, vacc = fz;
#pragma unroll
      for (int k = 0; k < 4; ++k) {
        bf16x8 bk = *(const bf16x8*)(WK + (size_t)(nt * 16 + l16) * HD + k * 32 + quad * 8);
        bf16x8 bv = *(const bf16x8*)(WV + (size_t)(nt * 16 + l16) * HD + k * 32 + quad * 8);
        kacc = mfma16(a[k], bk, kacc);
        vacc = mfma16(a[k], bv, vacc);
      }
      float kb = QKVB[wbase + 128 + nt * 16 + l16];
      float vb = QKVB[wbase + 256 + nt * 16 + l16];
      int d = nt * 16 + l16;
      int kc = nt * 2 + (l16 >> 3);  // d>>3
#pragma unroll
      for (int r = 0; r < 4; ++r) {
        int t = tb + quad * 4 + r;
        Kh[t * 32 + ((kc ^ (t & 3)) << 3) + (l16 & 7)] = f2bf(kacc[r] + kb);
        float vv = (t < NTOK) ? (vacc[r] + vb) : 0.f;  // zero pad rows (0*garbage=NaN guard)
        Vh[d * 128 + (((t >> 3) ^ l16) << 3) + (t & 7)] = f2bf(vv);
      }
    }
  }
  __syncthreads();  // the ONLY barrier: K/V halves built by both waves of the head

  // ---- phase 2: 4 query M-tiles per wave, fully independent ----
  const float scl = 0.17677669529663687f * 1.4426950408889634f;  // 1/sqrt(32)*log2(e)
  for (int qmt = 0; qmt < 4; ++qmt) {
    int qb = (half * 4 + qmt) * 16;
    int arow = qb + l16; if (arow > 120) arow = 120;
    bf16x8 a[4];
#pragma unroll
    for (int k = 0; k < 4; ++k)
      a[k] = *(const bf16x8*)(Xs + (size_t)arow * HD + k * 32 + quad * 8);
#pragma unroll
    for (int nt = 0; nt < 2; ++nt) {
      f32x4 qacc = fz;
#pragma unroll
      for (int k = 0; k < 4; ++k)
        qacc = mfma16(a[k], *(const bf16x8*)(WQ + (size_t)(nt * 16 + l16) * HD + k * 32 + quad * 8), qacc);
      float qbias = QKVB[wbase + nt * 16 + l16];
      int kc = nt * 2 + (l16 >> 3);
#pragma unroll
      for (int r = 0; r < 4; ++r) {
        int m = quad * 4 + r;  // local q-tile row
        Pw[m * 32 + ((kc ^ (m & 3)) << 3) + (l16 & 7)] = f2bf((qacc[r] + qbias) * scl);
      }
    }
    // logits (K-dim = 32 = single mfma k-step)
    bf16x8 qa = *(const bf16x8*)(Pw + l16 * 32 + ((quad ^ (l16 & 3)) << 3));
    f32x4 lg[8];
#pragma unroll
    for (int nt = 0; nt < 8; ++nt)
      lg[nt] = mfma16(qa, *(const bf16x8*)(Kh + (nt * 16 + l16) * 32 + ((quad ^ (l16 & 3)) << 3)), fz);
    if (l16 >= 9) lg[7] = (f32x4){-3e38f, -3e38f, -3e38f, -3e38f};  // mask cols 121..127
    float rinv[4];
#pragma unroll
    for (int r = 0; r < 4; ++r) {
      float mx = lg[0][r];
#pragma unroll
      for (int nt = 1; nt < 8; ++nt) mx = fmaxf(mx, lg[nt][r]);
      mx = fmaxf(mx, __shfl_xor(mx, 1)); mx = fmaxf(mx, __shfl_xor(mx, 2));
      mx = fmaxf(mx, __shfl_xor(mx, 4)); mx = fmaxf(mx, __shfl_xor(mx, 8));
      float e[8], sum = 0.f;
#pragma unroll
      for (int nt = 0; nt < 8; ++nt) {
        e[nt] = __builtin_amdgcn_exp2f(lg[nt][r] - mx);  // exp2-domain softmax
        sum += e[nt];
      }
      sum += __shfl_xor(sum, 1); sum += __shfl_xor(sum, 2);
      sum += __shfl_xor(sum, 4); sum += __shfl_xor(sum, 8);
      rinv[r] = __builtin_amdgcn_rcpf(sum);  // normalize deferred to O epilogue
      int qr = quad * 4 + r;
#pragma unroll
      for (int nt = 0; nt < 8; ++nt)
        Pw[qr * 128 + (((nt * 2 + (l16 >> 3)) ^ qr) << 3) + (l16 & 7)] = f2bf(e[nt]);
    }
    // P @ V (K-dim = 128 tokens = 4 k-steps)
#pragma unroll
    for (int pnt = 0; pnt < 2; ++pnt) {
      f32x4 oacc = fz;
#pragma unroll
      for (int ks = 0; ks < 4; ++ks) {
        bf16x8 pa = *(const bf16x8*)(Pw + l16 * 128 + (((ks * 4 + quad) ^ l16) << 3));
        bf16x8 vb = *(const bf16x8*)(Vh + (pnt * 16 + l16) * 128 + (((ks * 4 + quad) ^ l16) << 3));
        oacc = mfma16(pa, vb, oacc);
      }
#pragma unroll
      for (int r = 0; r < 4; ++r) {
        int row = qb + quad * 4 + r;
        if (row < NTOK)
          O[(size_t)seq * (NTOK * HD) + (size_t)row * HD + head * 32 + pnt * 16 + l16] =
              f2bf(oacc[r] * rinv[r]);
      }
    }
  }
}

// ---------------- proj GEMM + residual + LN1 (in-place on X) -------------
__global__ __launch_bounds__(256) void projln_kernel(
    u16* __restrict__ X, const u16* __restrict__ O,
    const u16* __restrict__ WP, const float* __restrict__ PB,
    const float* __restrict__ G, const float* __restrict__ Bt, int layer) {
  __shared__ u16 as_[32 * 136];
  __shared__ float ct[32 * 132];
  int r0 = blockIdx.x * 32, tid = threadIdx.x;
  int wave = tid >> 6, lane = tid & 63, l16 = lane & 15, quad = lane >> 4;
  const f32x4 fz = {0.f, 0.f, 0.f, 0.f};
  for (int c = tid; c < 32 * 16; c += 256) {
    int row = c >> 4, g = c & 15;
    *(uint4*)(as_ + row * 136 + g * 8) = *(const uint4*)(O + (size_t)(r0 + row) * HD + g * 8);
  }
  __syncthreads();
  f32x4 acc[2][2] = {{fz, fz}, {fz, fz}};
#pragma unroll
  for (int k = 0; k < 4; ++k) {
    bf16x8 a0 = *(const bf16x8*)(as_ + l16 * 136 + k * 32 + quad * 8);
    bf16x8 a1 = *(const bf16x8*)(as_ + (16 + l16) * 136 + k * 32 + quad * 8);
#pragma unroll
    for (int n = 0; n < 2; ++n) {
      int nt = wave * 2 + n;
      bf16x8 bf = *(const bf16x8*)(WP + ((size_t)(layer * 128 + nt * 16 + l16)) * HD + k * 32 + quad * 8);
      acc[0][n] = mfma16(a0, bf, acc[0][n]);
      acc[1][n] = mfma16(a1, bf, acc[1][n]);
    }
  }
  for (int mt = 0; mt < 2; ++mt)
    for (int n = 0; n < 2; ++n) {
      int nt = wave * 2 + n;
#pragma unroll
      for (int r = 0; r < 4; ++r)
        ct[(mt * 16 + quad * 4 + r) * 132 + nt * 16 + l16] = acc[mt][n][r];
    }
  __syncthreads();
  int row = tid >> 3, l8 = tid & 7;
  size_t R = (size_t)(r0 + row);
  float v[16], sum = 0.f, ssq = 0.f;
#pragma unroll
  for (int i = 0; i < 16; ++i) {
    int c = l8 * 16 + i;
    float t = ct[row * 132 + c] + PB[layer * 128 + c] + bf2f(X[R * HD + c]);
    v[i] = t; sum += t; ssq += t * t;
  }
  for (int m = 1; m <= 4; m <<= 1) { sum += __shfl_xor(sum, m, 64); ssq += __shfl_xor(ssq, m, 64); }
  float mean = sum * (1.f / 128.f);
  float var = ssq * (1.f / 128.f) - mean * mean;
  float rstd = rsqrtf(var + EPSF);
#pragma unroll
  for (int i = 0; i < 16; ++i) {
    int c = l8 * 16 + i;
    X[R * HD + c] = f2bf((v[i] - mean) * rstd * G[layer * 128 + c] + Bt[layer * 128 + c]);
  }
}

// ---------------- ff1+relu+ff2 + residual + LN2 (in-place on X) ----------
__global__ __launch_bounds__(256) void ffn_kernel(
    u16* __restrict__ X,
    const u16* __restrict__ W1, const float* __restrict__ B1,
    const u16* __restrict__ W2, const float* __restrict__ B2,
    const float* __restrict__ G, const float* __restrict__ Bt, int layer) {
  __shared__ u16 as_[32 * 136];
  __shared__ u16 hs[32 * 136];
  __shared__ float ct[32 * 132];
  int r0 = blockIdx.x * 32, tid = threadIdx.x;
  int wave = tid >> 6, lane = tid & 63, l16 = lane & 15, quad = lane >> 4;
  const f32x4 fz = {0.f, 0.f, 0.f, 0.f};
  for (int c = tid; c < 32 * 16; c += 256) {
    int row = c >> 4, g = c & 15;
    *(uint4*)(as_ + row * 136 + g * 8) = *(const uint4*)(X + (size_t)(r0 + row) * HD + g * 8);
  }
  __syncthreads();
  f32x4 acc[2][2] = {{fz, fz}, {fz, fz}};
#pragma unroll
  for (int k = 0; k < 4; ++k) {
    bf16x8 a0 = *(const bf16x8*)(as_ + l16 * 136 + k * 32 + quad * 8);
    bf16x8 a1 = *(const bf16x8*)(as_ + (16 + l16) * 136 + k * 32 + quad * 8);
#pragma unroll
    for (int n = 0; n < 2; ++n) {
      int nt = wave * 2 + n;
      bf16x8 bf = *(const bf16x8*)(W1 + ((size_t)(layer * 128 + nt * 16 + l16)) * HD + k * 32 + quad * 8);
      acc[0][n] = mfma16(a0, bf, acc[0][n]);
      acc[1][n] = mfma16(a1, bf, acc[1][n]);
    }
  }
  for (int mt = 0; mt < 2; ++mt)
    for (int n = 0; n < 2; ++n) {
      int nt = wave * 2 + n;
      int col = nt * 16 + l16;
      float b1 = B1[layer * 128 + col];
#pragma unroll
      for (int r = 0; r < 4; ++r)
        hs[(mt * 16 + quad * 4 + r) * 136 + col] = f2bf(fmaxf(acc[mt][n][r] + b1, 0.f));
    }
  __syncthreads();
  f32x4 acc2[2][2] = {{fz, fz}, {fz, fz}};
#pragma unroll
  for (int k = 0; k < 4; ++k) {
    bf16x8 a0 = *(const bf16x8*)(hs + l16 * 136 + k * 32 + quad * 8);
    bf16x8 a1 = *(const bf16x8*)(hs + (16 + l16) * 136 + k * 32 + quad * 8);
#pragma unroll
    for (int n = 0; n < 2; ++n) {
      int nt = wave * 2 + n;
      bf16x8 bf = *(const bf16x8*)(W2 + ((size_t)(layer * 128 + nt * 16 + l16)) * HD + k * 32 + quad * 8);
      acc2[0][n] = mfma16(a0, bf, acc2[0][n]);
      acc2[1][n] = mfma16(a1, bf, acc2[1][n]);
    }
  }
  for (int mt = 0; mt < 2; ++mt)
    for (int n = 0; n < 2; ++n) {
      int nt = wave * 2 + n;
#pragma unroll
      for (int r = 0; r < 4; ++r)
        ct[(mt * 16 + quad * 4 + r) * 132 + nt * 16 + l16] = acc2[mt][n][r];
    }
  __syncthreads();
  int row = tid >> 3, l8 = tid & 7;
  size_t R = (size_t)(r0 + row);
  float v[16], sum = 0.f, ssq = 0.f;
#pragma unroll
  for (int i = 0; i < 16; ++i) {
    int c = l8 * 16 + i;
    float t = ct[row * 132 + c] + B2[layer * 128 + c] + bf2f(as_[row * 136 + c]);
    v[i] = t; sum += t; ssq += t * t;
  }
  for (int m = 1; m <= 4; m <<= 1) { sum += __shfl_xor(sum, m, 64); ssq += __shfl_xor(ssq, m, 64); }
  float mean = sum * (1.f / 128.f);
  float var = ssq * (1.f / 128.f) - mean * mean;
  float rstd = rsqrtf(var + EPSF);
#pragma unroll
  for (int i = 0; i < 16; ++i) {
    int c = l8 * 16 + i;
    X[R * HD + c] = f2bf((v[i] - mean) * rstd * G[layer * 128 + c] + Bt[layer * 128 + c]);
  }
}

// ---------------- final GEMM (M=2048,K=15488,N=256), split-K=16 ----------
__global__ __launch_bounds__(256, 2) void outgemm_kernel(
    const u16* __restrict__ X, const u16* __restrict__ WO, float* __restrict__ PART) {
  __shared__ u16 as_[64 * 136];
  int mtile = blockIdx.x, j = blockIdx.y;
  int tid = threadIdx.x, wave = tid >> 6, lane = tid & 63, l16 = lane & 15, quad = lane >> 4;
  int s0 = mtile * 64;
  int k0 = (j * 484) / 16, k1 = ((j + 1) * 484) / 16;  // k-steps of 32 over K=15488
  const f32x4 fz = {0.f, 0.f, 0.f, 0.f};
  f32x4 acc[4][4];
  for (int a = 0; a < 4; ++a) for (int b = 0; b < 4; ++b) acc[a][b] = fz;
  for (int kb = k0; kb < k1; kb += 4) {
    int nst = (k1 - kb < 4) ? (k1 - kb) : 4;
    __syncthreads();
    int chunks = 64 * 4 * nst;
    for (int c = tid; c < chunks; c += 256) {
      int row = c / (4 * nst), g = c % (4 * nst);
      *(uint4*)(as_ + row * 136 + g * 8) =
          *(const uint4*)(X + (size_t)(s0 + row) * 15488 + kb * 32 + g * 8);
    }
    __syncthreads();
    for (int kk = 0; kk < nst; ++kk) {
      bf16x8 af[4];
#pragma unroll
      for (int mt = 0; mt < 4; ++mt)
        af[mt] = *(const bf16x8*)(as_ + (mt * 16 + l16) * 136 + kk * 32 + quad * 8);
#pragma unroll
      for (int n = 0; n < 4; ++n) {
        int nt = wave * 4 + n;
        bf16x8 bf = *(const bf16x8*)(WO + (size_t)(nt * 16 + l16) * 15488 +
                                     (size_t)(kb + kk) * 32 + quad * 8);
#pragma unroll
        for (int mt = 0; mt < 4; ++mt) acc[mt][n] = mfma16(af[mt], bf, acc[mt][n]);
      }
    }
  }
  for (int mt = 0; mt < 4; ++mt)
    for (int n = 0; n < 4; ++n) {
      int nt = wave * 4 + n;
#pragma unroll
      for (int r = 0; r < 4; ++r) {
        int row = s0 + mt * 16 + quad * 4 + r;
        PART[((size_t)j * 2048 + row) * 256 + nt * 16 + l16] = acc[mt][n][r];
      }
    }
}

// ---------------- reduce split-K partials + bias + final LN --------------
__global__ __launch_bounds__(256) void lnf_kernel(
    const float* __restrict__ PART, const float* __restrict__ BO,
    const float* __restrict__ G, const float* __restrict__ Bt, float* __restrict__ OUT) {
  int s = blockIdx.x * 4 + (threadIdx.x >> 6);  // one wave per sequence
  int lane = threadIdx.x & 63;
  float v[4], sum = 0.f, ssq = 0.f;
#pragma unroll
  for (int i = 0; i < 4; ++i) {
    int c = lane + i * 64;
    float t = BO[c];
    for (int jj = 0; jj < 16; ++jj) t += PART[((size_t)jj * 2048 + s) * 256 + c];
    v[i] = t; sum += t; ssq += t * t;
  }
  for (int m = 1; m <= 32; m <<= 1) { sum += __shfl_xor(sum, m, 64); ssq += __shfl_xor(ssq, m, 64); }
  float mean = sum * (1.f / 256.f);
  float var = ssq * (1.f / 256.f) - mean * mean;
  float rstd = rsqrtf(var + EPSF);
#pragma unroll
  for (int i = 0; i < 4; ++i) {
    int c = lane + i * 64;
    OUT[(size_t)s * 256 + c] = (v[i] - mean) * rstd * G[c] + Bt[c];
  }
}

extern "C" void kernel_launch(void* const* d_in, const int* in_sizes, int n_in,
                              void* d_out, int out_size, void* d_ws, size_t ws_size,
                              hipStream_t stream) {
  const float* forest = (const float*)d_in[0];
  const int* adj      = (const int*)d_in[1];
  const int* perm     = (const int*)d_in[2];
  const float* w_in   = (const float*)d_in[3];
  const float* b_in   = (const float*)d_in[4];
  const float* qkv_w  = (const float*)d_in[5];
  const float* qkv_b  = (const float*)d_in[6];
  const float* proj_w = (const float*)d_in[7];
  const float* proj_b = (const float*)d_in[8];
  const float* ff1_w  = (const float*)d_in[9];
  const float* ff1_b  = (const float*)d_in[10];
  const float* ff2_w  = (const float*)d_in[11];
  const float* ff2_b  = (const float*)d_in[12];
  const float* ln1_g  = (const float*)d_in[13];
  const float* ln1_b  = (const float*)d_in[14];
  const float* ln2_g  = (const float*)d_in[15];
  const float* ln2_b  = (const float*)d_in[16];
  const float* w_out  = (const float*)d_in[17];
  const float* b_out  = (const float*)d_in[18];
  const float* lnf_g  = (const float*)d_in[19];
  const float* lnf_b  = (const float*)d_in[20];

  // workspace map (bytes): bf16 weights 8,323,072 | X 63,438,848 | O 63,438,848 | PART 33,554,432
  char* ws = (char*)d_ws;
  u16* WB = (u16*)ws;
  u16* X  = (u16*)(ws + 8323072);
  u16* O  = (u16*)(ws + 8323072 + 63438848);
  float* PART = (float*)(ws + 8323072 + 2 * (size_t)63438848);

  u16* WQKV  = WB;
  u16* WPROJ = WB + 98304;
  u16* WFF1  = WB + 131072;
  u16* WFF2  = WB + 163840;
  u16* WOUT  = WB + 196608;

  convw_kernel<<<16256, 256, 0, stream>>>(qkv_w, proj_w, ff1_w, ff2_w, w_out, WB);
  inproj_kernel<<<2048, 256, 0, stream>>>(forest, adj, perm, w_in, b_in, X);
  for (int layer = 0; layer < 2; ++layer) {
    attn_kernel<<<4096, 256, 0, stream>>>(X, O, WQKV, qkv_b, layer);
    projln_kernel<<<7744, 256, 0, stream>>>(X, O, WPROJ, proj_b, ln1_g, ln1_b, layer);
    ffn_kernel<<<7744, 256, 0, stream>>>(X, WFF1, ff1_b, WFF2, ff2_b, ln2_g, ln2_b, layer);
  }
  outgemm_kernel<<<dim3(32, 16), 256, 0, stream>>>(X, WOUT, PART);
  lnf_kernel<<<512, 256, 0, stream>>>(PART, b_out, lnf_g, lnf_b, (float*)d_out);
}